// Round 7
// baseline (138.131 us; speedup 1.0000x reference)
//
#include <hip/hip_runtime.h>

#define SP    65536      // 16*64*64 spatial voxels
#define DD    16
#define HH    64
#define WW    64
#define CIN   64
#define COUT  64

#define RP    68         // attn LDS row pitch (floats): 272B -> 4-bank shift/row

#define LOG2E 1.44269504f

// ws layout (fp32): q [64][SP] | k [64][SP] | v [64][SP]   (48 MB)
// LESSON LEDGER:
// r10: bf16 STORAGE of k fails accuracy. Intermediates fp32 in HBM.
// r11: proj = bf16x3 split MFMA (wh*xh+wh*xl+wl*xh); q pre-scaled by LOG2E.
// r12: no-LDS attn -> compiler hoists loads -> 374MB scratch spill.
// r13: (a) I-cache theory FALSIFIED. (b) <=1536-block proj = TLP loss
//      (3072 is the proven grid). (c) in-register w split from global WORKS.
// r14: min-waves launch_bounds + live per-thread ARRAYS -> spill. Cap is OK
//      only when body state is small and statically indexed.
// r15: attn v7 (1 float4/thread, 4096 blocks, pitch 68): attn <43us.
// r16: proj 128-tile (1536 blocks) +8.6us - reverted. Noise band +-5-8us:
//      only multi-10us structural changes are readable per round.
// r17 (this): attn v9 = v8 + launch_bounds(256,5) (VGPR cap 102 -> 5
// waves/SIMD; no arrays so spill risk low; spill would show as attn in
// top-5 w/ WRITE>>16MB). proj v5 = 64-pos v2 shape + w split in-register
// (r13-proven), LDS 18.4KB -> 8 blk/CU.

typedef __attribute__((ext_vector_type(8))) short bf16x8;   // 8 bf16 = 4 VGPRs
typedef __attribute__((ext_vector_type(4))) float f32x4;    // MFMA acc

__device__ __forceinline__ unsigned short f2bf(float f) {   // RNE f32->bf16
    const unsigned u = __float_as_uint(f);
    return (unsigned short)((u + 0x7FFFu + ((u >> 16) & 1u)) >> 16);
}
__device__ __forceinline__ float bf2f(unsigned short h) {
    return __uint_as_float((unsigned)h << 16);
}

// proj v5: per block 64 positions x all 64 outs, one matrix (grid.y);
// 3072 blocks (proven grid). x staged TRANSPOSED [j][c] hi/lo in LDS
// (pitch 72: b128 frag reads 2-way = free). w split IN-REGISTER from
// global (r13-proven; 16KB w is L2/L3-resident). A/B both pack 8
// consecutive cin -> same k-permutation on both operands -> contraction
// layout-permutation-safe.
// C/D layout (HW-verified): col=lane&15, row=(lane>>4)*4+reg.
__global__ __launch_bounds__(256) void proj(const float* __restrict__ x,
                                            const float* __restrict__ wq,
                                            const float* __restrict__ wk,
                                            const float* __restrict__ wv,
                                            float* __restrict__ q,
                                            float* __restrict__ k,
                                            float* __restrict__ v) {
    __shared__ __align__(16) unsigned short xh [64][72];   // [j][c] hi, 9.2 KB
    __shared__ __align__(16) unsigned short xlo[64][72];   // [j][c] lo -> 18.4 KB

    const int t  = threadIdx.x;
    const int p0 = blockIdx.x * 64;
    const int m  = blockIdx.y;

    const float* __restrict__ wsel = (m == 0) ? wq : (m == 1) ? wk : wv;
    float* __restrict__       osel = (m == 0) ? q  : (m == 1) ? k  : v;

    // stage x[c][p0+j] -> xh/xlo[j][c], split hi/lo. Channel pairs (c2,c2+1)
    // packed into one u32 LDS write (residual exact: |x-hi| <= 2^-9|x|).
#pragma unroll
    for (int i = 0; i < 2; ++i) {
        const int f  = t + 256 * i;          // 0..511
        const int c2 = (f >> 4) * 2;
        const int jj = f & 15;
        const float4 a = *(const float4*)(x + c2 * SP + p0 + jj * 4);
        const float4 b = *(const float4*)(x + (c2 + 1) * SP + p0 + jj * 4);
        const float* af = (const float*)&a;
        const float* bf = (const float*)&b;
#pragma unroll
        for (int e = 0; e < 4; ++e) {
            const int j = jj * 4 + e;
            const unsigned short ah = f2bf(af[e]);
            const unsigned short bh = f2bf(bf[e]);
            const unsigned short al = f2bf(af[e] - bf2f(ah));
            const unsigned short bl = f2bf(bf[e] - bf2f(bh));
            *(unsigned*)&xh [j][c2] = (unsigned)ah | ((unsigned)bh << 16);
            *(unsigned*)&xlo[j][c2] = (unsigned)al | ((unsigned)bl << 16);
        }
    }

    const int lane  = t & 63;
    const int wid   = t >> 6;                // wave -> 16-out slice
    const int lo16  = lane & 15;
    const int lg    = lane >> 4;             // 0..3 k-group
    const int otile = wid * 16;

    // in-register w split: A-frags (2 k-chunks), vector loads from global
    bf16x8 Ah[2], Al[2];
#pragma unroll
    for (int ch = 0; ch < 2; ++ch) {
        const float* src = wsel + (otile + lo16) * CIN + ch * 32 + lg * 8;
        float fv[8];
        *(float4*)&fv[0] = *(const float4*)src;
        *(float4*)&fv[4] = *(const float4*)(src + 4);
        bf16x8 hv, lv;
#pragma unroll
        for (int e = 0; e < 8; ++e) {
            const unsigned short hb = f2bf(fv[e]);
            hv[e] = (short)hb;
            lv[e] = (short)f2bf(fv[e] - bf2f(hb));
        }
        Ah[ch] = hv;
        Al[ch] = lv;
    }
    __syncthreads();

    const float scale = (m == 0) ? LOG2E : 1.f;   // fold exp2 prescale into q

#pragma unroll
    for (int jt = 0; jt < 4; ++jt) {
        const int jr = jt * 16 + lo16;
        const bf16x8 Bh0 = *(const bf16x8*)&xh [jr][lg * 8];
        const bf16x8 Bl0 = *(const bf16x8*)&xlo[jr][lg * 8];
        const bf16x8 Bh1 = *(const bf16x8*)&xh [jr][32 + lg * 8];
        const bf16x8 Bl1 = *(const bf16x8*)&xlo[jr][32 + lg * 8];
        f32x4 hh = {0.f, 0.f, 0.f, 0.f};     // 3 independent chains for ILP
        f32x4 hl = {0.f, 0.f, 0.f, 0.f};
        f32x4 lh = {0.f, 0.f, 0.f, 0.f};
        hh = __builtin_amdgcn_mfma_f32_16x16x32_bf16(Ah[0], Bh0, hh, 0, 0, 0);
        hl = __builtin_amdgcn_mfma_f32_16x16x32_bf16(Ah[0], Bl0, hl, 0, 0, 0);
        lh = __builtin_amdgcn_mfma_f32_16x16x32_bf16(Al[0], Bh0, lh, 0, 0, 0);
        hh = __builtin_amdgcn_mfma_f32_16x16x32_bf16(Ah[1], Bh1, hh, 0, 0, 0);
        hl = __builtin_amdgcn_mfma_f32_16x16x32_bf16(Ah[1], Bl1, hl, 0, 0, 0);
        lh = __builtin_amdgcn_mfma_f32_16x16x32_bf16(Al[1], Bh1, lh, 0, 0, 0);
        float* op = osel + (otile + lg * 4) * SP + p0 + jt * 16 + lo16;
#pragma unroll
        for (int r = 0; r < 4; ++r)
            op[r * SP] = (hh[r] + hl[r] + lh[r]) * scale;   // 4 rows x 64B, coalesced
    }
}

// DPP shifts within 16-lane rows; bound_ctrl=1 -> out-of-row reads 0 =
// exactly the w-boundary zero-pad (wg==0/15 are DPP row boundaries).
__device__ __forceinline__ float dpp_shr1(float x) {   // lane i <- lane i-1
    return __int_as_float(__builtin_amdgcn_mov_dpp(__float_as_int(x), 0x111, 0xf, 0xf, true));
}
__device__ __forceinline__ float dpp_shl1(float x) {   // lane i <- lane i+1
    return __int_as_float(__builtin_amdgcn_mov_dpp(__float_as_int(x), 0x101, 0xf, 0xf, true));
}

// attn v9 walk: thread = 1 float4 output; 9 (kd,kh) rows, 3 rel scalars.
// AXIS 0/1: rc is row-constant -> folded into krow once (bit-identical).
template<int AXIS>
__device__ __forceinline__ void attn_walk(const float* __restrict__ kt,
                                          const float* __restrict__ vt,
                                          const float (&ql)[4],
                                          float r0, float r1, float r2,
                                          int wg, int hl, int dl,
                                          float (&s)[4], float (&a)[4]) {
#pragma unroll
    for (int kd = 0; kd < 3; ++kd) {
        const float rdd = (kd == 0) ? r0 : (kd == 1) ? r1 : r2;
#pragma unroll
        for (int kh = 0; kh < 3; ++kh) {
            const float rkh = (kh == 0) ? r0 : (kh == 1) ? r1 : r2;
            const float rr  = (AXIS == 0) ? rdd : rkh;
            const int off = ((dl + kd) * 6 + hl + kh) * RP + wg * 4;
            const float4 km = *(const float4*)(kt + off);
            const float4 vm = *(const float4*)(vt + off);
            const float kl = dpp_shr1(km.w), kr = dpp_shl1(km.x);
            const float vl = dpp_shr1(vm.w), vr = dpp_shl1(vm.x);
            float krow[6] = { kl, km.x, km.y, km.z, km.w, kr };
            const float vrow[6] = { vl, vm.x, vm.y, vm.z, vm.w, vr };
            if (AXIS != 2) {                 // hoist row-constant rel
#pragma unroll
                for (int j = 0; j < 6; ++j) krow[j] += rr;
            }
#pragma unroll
            for (int wi = 0; wi < 4; ++wi) {
                const float qv = ql[wi];
#pragma unroll
                for (int kw = 0; kw < 3; ++kw) {
                    const float arg = (AXIS == 2)
                                    ? (krow[wi + kw] + ((kw == 0) ? r0 : (kw == 1) ? r1 : r2))
                                    : krow[wi + kw];
                    const float e = __builtin_amdgcn_exp2f(qv * arg);
                    s[wi] += e;
                    a[wi] = fmaf(e, vrow[wi + kw], a[wi]);
                }
            }
        }
    }
}

// attn v9: block = (dtile4 x htile4, o) -> 4d x 4h x 64w outputs of one
// channel; thread = ONE float4 (1d x 4w). LDS halo [6][6][RP] k+v = 19.6KB.
// launch_bounds(256,5): VGPR cap 102 -> 5 waves/SIMD. Body has no live
// arrays (r14 spill risk absent); cap just limits ds_read in-flight count.
// Single-pass softmax; OOB: k=0+rel in softmax, v=0.
__global__ __launch_bounds__(256, 5) void attn(const float* __restrict__ kbuf,
                                               const float* __restrict__ vbuf,
                                               const float* __restrict__ qbuf,
                                               const float* __restrict__ rel_d,
                                               const float* __restrict__ rel_h,
                                               const float* __restrict__ rel_w,
                                               float* __restrict__ out) {
    __shared__ float kt[36 * RP];    // [nd][nh][w], 9.8 KB
    __shared__ float vt[36 * RP];

    const int dt = blockIdx.x;       // 0..3
    const int ht = blockIdx.y;       // 0..15
    const int o  = blockIdx.z;       // 0..63

    const int d0 = dt * 4;
    const int h0 = ht * 4;
    const int t  = threadIdx.x;

    const float* __restrict__ kc = kbuf + o * SP;
    const float* __restrict__ vc = vbuf + o * SP;

    // stage k,v halo tiles: 2 * 36 rows * 16 float4 = 1152 float4
#pragma unroll
    for (int i = 0; i < 5; ++i) {
        const int idx = t + 256 * i;
        if (idx < 1152) {
            const bool isv = idx >= 576;
            const int rem  = isv ? idx - 576 : idx;
            const int row  = rem >> 4;         // 0..35
            const int j    = rem & 15;
            const int nd   = row / 6;
            const int nh   = row - nd * 6;
            const int dpg  = d0 - 1 + nd;
            const int hpg  = h0 - 1 + nh;
            float4 val = make_float4(0.f, 0.f, 0.f, 0.f);
            if ((unsigned)dpg < (unsigned)DD && (unsigned)hpg < (unsigned)HH) {
                const float* src = (isv ? vc : kc) + (dpg * HH + hpg) * WW + j * 4;
                val = *(const float4*)src;
            }
            *(float4*)((isv ? vt : kt) + row * RP + j * 4) = val;
        }
    }

    const int wg = t & 15;           // float4 in w
    const int hl = (t >> 4) & 3;     // local h
    const int dl = t >> 6;           // local d (== wave id)

    const int dabs = d0 + dl;
    const int habs = h0 + hl;

    float ql[4];
    {
        const float4 q4 = *(const float4*)(qbuf + o * SP + (dabs * HH + habs) * WW + wg * 4);
        ql[0] = q4.x; ql[1] = q4.y;            // q pre-scaled by LOG2E in proj
        ql[2] = q4.z; ql[3] = q4.w;
    }

    __syncthreads();

    float s[4] = {};
    float a[4] = {};

    if (o < 21) {
        attn_walk<0>(kt, vt, ql, rel_d[o * 3], rel_d[o * 3 + 1], rel_d[o * 3 + 2],
                     wg, hl, dl, s, a);
    } else if (o < 42) {
        const int b = o - 21;
        attn_walk<1>(kt, vt, ql, rel_h[b * 3], rel_h[b * 3 + 1], rel_h[b * 3 + 2],
                     wg, hl, dl, s, a);
    } else {
        const int b = o - 42;
        attn_walk<2>(kt, vt, ql, rel_w[b * 3], rel_w[b * 3 + 1], rel_w[b * 3 + 2],
                     wg, hl, dl, s, a);
    }

    float4 ov;
    ov.x = a[0] * __builtin_amdgcn_rcpf(s[0]);
    ov.y = a[1] * __builtin_amdgcn_rcpf(s[1]);
    ov.z = a[2] * __builtin_amdgcn_rcpf(s[2]);
    ov.w = a[3] * __builtin_amdgcn_rcpf(s[3]);
    *(float4*)(out + o * SP + (dabs * HH + habs) * WW + wg * 4) = ov;
}

extern "C" void kernel_launch(void* const* d_in, const int* in_sizes, int n_in,
                              void* d_out, int out_size, void* d_ws, size_t ws_size,
                              hipStream_t stream) {
    const float* x     = (const float*)d_in[0];
    const float* w_q   = (const float*)d_in[1];
    const float* w_k   = (const float*)d_in[2];
    const float* w_v   = (const float*)d_in[3];
    const float* rel_d = (const float*)d_in[4];
    const float* rel_h = (const float*)d_in[5];
    const float* rel_w = (const float*)d_in[6];
    float* out = (float*)d_out;

    float* ws = (float*)d_ws;
    float* q  = ws;
    float* k  = ws + (size_t)COUT * SP;
    float* v  = ws + 2 * (size_t)COUT * SP;

    proj<<<dim3(SP / 64, 3), 256, 0, stream>>>(x, w_q, w_k, w_v, q, k, v);
    attn<<<dim3(4, 16, 64), 256, 0, stream>>>(k, v, q, rel_d, rel_h, rel_w, out);
}

// Round 8
// 115.747 us; speedup vs baseline: 1.1934x; 1.1934x over previous
//
#include <hip/hip_runtime.h>

#define SP    65536      // 16*64*64 spatial voxels
#define DD    16
#define HH    64
#define WW    64
#define CIN   64
#define COUT  64

#define LOG2E 1.44269504f

// ws layout (fp32): q [64][SP] | k [64][SP] | v [64][SP]   (48 MB)
// LESSON LEDGER:
// r10: bf16 STORAGE of k fails accuracy. Intermediates fp32 in HBM.
// r11: proj = bf16x3 split MFMA (wh*xh+wh*xl+wl*xh); q pre-scaled by LOG2E.
// r12: no-LDS attn w/ FULLY-UNROLLED walk -> hoisted loads -> 374MB spill.
//      Failure mode = unbounded hoist, NOT direct-global per se.
// r13: I-cache theory FALSIFIED.
// r14+r17: ANY min-waves launch_bounds on attn spills (r17: VGPR 48,
//      WRITE 104MB). attn must run uncapped.
// r16+r17: in-register w split is the PROJ regression (~40-45us in all 3
//      variants vs 22us w-via-LDS) - r13(c) corrected. proj v2 restored.
// r18 (this): attn v10 = v7 shape (1 float4/thread) reading k,v DIRECTLY
// from global (no LDS, no barrier): per-block tap set is L1-resident (9KB
// x2), so re-reads are L1-served. kd loop unroll(1) bounds in-flight loads
// (~6 float4) to prevent the r12 hoist-spill. Tripwire: attn WRITE_SIZE
// must stay ~16.4MB (spill shows as WRITE >> output).

typedef __attribute__((ext_vector_type(8))) short bf16x8;   // 8 bf16 = 4 VGPRs
typedef __attribute__((ext_vector_type(4))) float f32x4;    // MFMA acc

__device__ __forceinline__ unsigned short f2bf(float f) {   // RNE f32->bf16
    const unsigned u = __float_as_uint(f);
    return (unsigned short)((u + 0x7FFFu + ((u >> 16) & 1u)) >> 16);
}
__device__ __forceinline__ float bf2f(unsigned short h) {
    return __uint_as_float((unsigned)h << 16);
}

// proj v2 (r11 form, known-good ~22us): per block 64 positions x all 64
// outs, one matrix (grid.y); 3072 blocks. K=64 in LDS once. x staged
// TRANSPOSED [j][c] hi/lo; w staged [o][c] hi/lo VIA LDS (r16/r17 lesson:
// in-register w split costs ~2x). A/B both pack 8 consecutive cin -> same
// k-permutation on both operands -> contraction layout-permutation-safe.
// C/D layout (HW-verified): col=lane&15, row=(lane>>4)*4+reg.
__global__ __launch_bounds__(256) void proj(const float* __restrict__ x,
                                            const float* __restrict__ wq,
                                            const float* __restrict__ wk,
                                            const float* __restrict__ wv,
                                            float* __restrict__ q,
                                            float* __restrict__ k,
                                            float* __restrict__ v) {
    __shared__ __align__(16) unsigned short xh [64][72];   // [j][c] hi, 9 KB
    __shared__ __align__(16) unsigned short xlo[64][72];   // [j][c] lo
    __shared__ __align__(16) unsigned short wh [64][72];   // [o][c] hi
    __shared__ __align__(16) unsigned short wlo[64][72];   // 36.9 KB -> 4 blk/CU

    const int t  = threadIdx.x;
    const int p0 = blockIdx.x * 64;
    const int m  = blockIdx.y;

    const float* __restrict__ wsel = (m == 0) ? wq : (m == 1) ? wk : wv;
    float* __restrict__       osel = (m == 0) ? q  : (m == 1) ? k  : v;

    // stage x[c][p0+j] -> xh/xlo[j][c], split hi/lo. Row pairs (c2, c2+1)
    // packed into one u32 LDS write (residual is exact: |x-hi| <= 2^-9|x|).
#pragma unroll
    for (int i = 0; i < 2; ++i) {
        const int f  = t + 256 * i;          // 0..511
        const int c2 = (f >> 4) * 2;
        const int jj = f & 15;
        const float4 a = *(const float4*)(x + c2 * SP + p0 + jj * 4);
        const float4 b = *(const float4*)(x + (c2 + 1) * SP + p0 + jj * 4);
        const float* af = (const float*)&a;
        const float* bf = (const float*)&b;
#pragma unroll
        for (int e = 0; e < 4; ++e) {
            const int j = jj * 4 + e;
            const unsigned short ah = f2bf(af[e]);
            const unsigned short bh = f2bf(bf[e]);
            const unsigned short al = f2bf(af[e] - bf2f(ah));
            const unsigned short bl = f2bf(bf[e] - bf2f(bh));
            *(unsigned*)&xh [j][c2] = (unsigned)ah | ((unsigned)bh << 16);
            *(unsigned*)&xlo[j][c2] = (unsigned)al | ((unsigned)bl << 16);
        }
    }
    // stage w[o][c] -> wh/wlo[o][c] (same orientation, b64 writes)
#pragma unroll
    for (int i = 0; i < 4; ++i) {
        const int f  = t + 256 * i;          // 0..1023
        const int o  = f >> 4;
        const int jj = f & 15;
        const float4 w4 = *(const float4*)(wsel + o * CIN + jj * 4);
        const float* wf = (const float*)&w4;
        unsigned short h0 = f2bf(wf[0]), h1 = f2bf(wf[1]);
        unsigned short h2 = f2bf(wf[2]), h3 = f2bf(wf[3]);
        unsigned short l0 = f2bf(wf[0] - bf2f(h0)), l1 = f2bf(wf[1] - bf2f(h1));
        unsigned short l2 = f2bf(wf[2] - bf2f(h2)), l3 = f2bf(wf[3] - bf2f(h3));
        *(uint2*)&wh [o][jj * 4] = make_uint2((unsigned)h0 | ((unsigned)h1 << 16),
                                              (unsigned)h2 | ((unsigned)h3 << 16));
        *(uint2*)&wlo[o][jj * 4] = make_uint2((unsigned)l0 | ((unsigned)l1 << 16),
                                              (unsigned)l2 | ((unsigned)l3 << 16));
    }
    __syncthreads();

    const int lane  = t & 63;
    const int wid   = t >> 6;                // wave -> 16-out slice
    const int lo16  = lane & 15;
    const int lg    = lane >> 4;             // 0..3 k-group
    const int otile = wid * 16;

    // A-fragments: w[otile+lo16][k-chunk], 8 consecutive cin, 16B aligned
    const bf16x8 Ah0 = *(const bf16x8*)&wh [otile + lo16][lg * 8];
    const bf16x8 Ah1 = *(const bf16x8*)&wh [otile + lo16][32 + lg * 8];
    const bf16x8 Al0 = *(const bf16x8*)&wlo[otile + lo16][lg * 8];
    const bf16x8 Al1 = *(const bf16x8*)&wlo[otile + lo16][32 + lg * 8];

    const float scale = (m == 0) ? LOG2E : 1.f;   // fold exp2 prescale into q

#pragma unroll
    for (int jt = 0; jt < 4; ++jt) {
        const int jr = jt * 16 + lo16;
        const bf16x8 Bh0 = *(const bf16x8*)&xh [jr][lg * 8];
        const bf16x8 Bl0 = *(const bf16x8*)&xlo[jr][lg * 8];
        const bf16x8 Bh1 = *(const bf16x8*)&xh [jr][32 + lg * 8];
        const bf16x8 Bl1 = *(const bf16x8*)&xlo[jr][32 + lg * 8];
        f32x4 hh = {0.f, 0.f, 0.f, 0.f};     // 3 independent chains for ILP
        f32x4 hl = {0.f, 0.f, 0.f, 0.f};
        f32x4 lh = {0.f, 0.f, 0.f, 0.f};
        hh = __builtin_amdgcn_mfma_f32_16x16x32_bf16(Ah0, Bh0, hh, 0, 0, 0);
        hl = __builtin_amdgcn_mfma_f32_16x16x32_bf16(Ah0, Bl0, hl, 0, 0, 0);
        lh = __builtin_amdgcn_mfma_f32_16x16x32_bf16(Al0, Bh0, lh, 0, 0, 0);
        hh = __builtin_amdgcn_mfma_f32_16x16x32_bf16(Ah1, Bh1, hh, 0, 0, 0);
        hl = __builtin_amdgcn_mfma_f32_16x16x32_bf16(Ah1, Bl1, hl, 0, 0, 0);
        lh = __builtin_amdgcn_mfma_f32_16x16x32_bf16(Al1, Bh1, lh, 0, 0, 0);
        float* op = osel + (otile + lg * 4) * SP + p0 + jt * 16 + lo16;
#pragma unroll
        for (int r = 0; r < 4; ++r)
            op[r * SP] = (hh[r] + hl[r] + lh[r]) * scale;   // 4 rows x 64B, coalesced
    }
}

// DPP shifts within 16-lane rows; bound_ctrl=1 -> out-of-row reads 0 =
// exactly the w-boundary zero-pad (each 16-lane DPP row spans the full
// w=0..63 extent via float4s, so row edges ARE the w=0/63 edges).
__device__ __forceinline__ float dpp_shr1(float x) {   // lane i <- lane i-1
    return __int_as_float(__builtin_amdgcn_mov_dpp(__float_as_int(x), 0x111, 0xf, 0xf, true));
}
__device__ __forceinline__ float dpp_shl1(float x) {   // lane i <- lane i+1
    return __int_as_float(__builtin_amdgcn_mov_dpp(__float_as_int(x), 0x101, 0xf, 0xf, true));
}

// attn v10 walk: thread = 1 float4 output; 9 (kd,kh) rows read DIRECTLY
// from global (L1-resident working set, ~9KB x2 per block region).
// unroll(1) on kd bounds in-flight loads to one kd-plane (6 float4) --
// r12's spill came from unbounded hoist, not from direct-global itself.
// AXIS 0/1: rc row-constant -> folded into krow (bit-identical).
// OOB rows: address clamped to 0, value zeroed (k=0 -> exp(q*rel), v=0).
template<int AXIS>
__device__ __forceinline__ void attn_walk(const float* __restrict__ kc,
                                          const float* __restrict__ vc,
                                          const float (&ql)[4],
                                          float r0, float r1, float r2,
                                          int wg, int dabs, int habs,
                                          float (&s)[4], float (&a)[4]) {
#pragma unroll 1
    for (int kd = 0; kd < 3; ++kd) {
        const float rdd = (kd == 0) ? r0 : (kd == 1) ? r1 : r2;
        const int dpg   = dabs - 1 + kd;
        const bool okd  = (unsigned)dpg < (unsigned)DD;
#pragma unroll
        for (int kh = 0; kh < 3; ++kh) {
            const float rkh = (kh == 0) ? r0 : (kh == 1) ? r1 : r2;
            const float rr  = (AXIS == 0) ? rdd : rkh;
            const int hpg   = habs - 1 + kh;
            const bool ok   = okd && ((unsigned)hpg < (unsigned)HH);
            const int off   = ok ? ((dpg * HH + hpg) * WW + wg * 4) : 0;
            float4 km = *(const float4*)(kc + off);
            float4 vm = *(const float4*)(vc + off);
            if (!ok) {
                km = make_float4(0.f, 0.f, 0.f, 0.f);
                vm = make_float4(0.f, 0.f, 0.f, 0.f);
            }
            const float kl = dpp_shr1(km.w), kr = dpp_shl1(km.x);
            const float vl = dpp_shr1(vm.w), vr = dpp_shl1(vm.x);
            float krow[6] = { kl, km.x, km.y, km.z, km.w, kr };
            const float vrow[6] = { vl, vm.x, vm.y, vm.z, vm.w, vr };
            if (AXIS != 2) {                 // hoist row-constant rel
#pragma unroll
                for (int j = 0; j < 6; ++j) krow[j] += rr;
            }
#pragma unroll
            for (int wi = 0; wi < 4; ++wi) {
                const float qv = ql[wi];
#pragma unroll
                for (int kw = 0; kw < 3; ++kw) {
                    const float arg = (AXIS == 2)
                                    ? (krow[wi + kw] + ((kw == 0) ? r0 : (kw == 1) ? r1 : r2))
                                    : krow[wi + kw];
                    const float e = __builtin_amdgcn_exp2f(qv * arg);
                    s[wi] += e;
                    a[wi] = fmaf(e, vrow[wi + kw], a[wi]);
                }
            }
        }
    }
}

// attn v10: block = (dtile4 x htile4, o) -> 4d x 4h x 64w outputs of one
// channel; thread = ONE float4 (1d x 4w). NO LDS, NO barrier: k,v taps
// stream from global (L1-served re-reads). No launch_bounds cap (r14/r17).
// Single-pass softmax.
__global__ __launch_bounds__(256) void attn(const float* __restrict__ kbuf,
                                            const float* __restrict__ vbuf,
                                            const float* __restrict__ qbuf,
                                            const float* __restrict__ rel_d,
                                            const float* __restrict__ rel_h,
                                            const float* __restrict__ rel_w,
                                            float* __restrict__ out) {
    const int dt = blockIdx.x;       // 0..3
    const int ht = blockIdx.y;       // 0..15
    const int o  = blockIdx.z;       // 0..63

    const int d0 = dt * 4;
    const int h0 = ht * 4;
    const int t  = threadIdx.x;

    const float* __restrict__ kc = kbuf + o * SP;
    const float* __restrict__ vc = vbuf + o * SP;

    const int wg = t & 15;           // float4 in w
    const int hl = (t >> 4) & 3;     // local h
    const int dl = t >> 6;           // local d (== wave id)

    const int dabs = d0 + dl;
    const int habs = h0 + hl;

    float ql[4];
    {
        const float4 q4 = *(const float4*)(qbuf + o * SP + (dabs * HH + habs) * WW + wg * 4);
        ql[0] = q4.x; ql[1] = q4.y;            // q pre-scaled by LOG2E in proj
        ql[2] = q4.z; ql[3] = q4.w;
    }

    float s[4] = {};
    float a[4] = {};

    if (o < 21) {
        attn_walk<0>(kc, vc, ql, rel_d[o * 3], rel_d[o * 3 + 1], rel_d[o * 3 + 2],
                     wg, dabs, habs, s, a);
    } else if (o < 42) {
        const int b = o - 21;
        attn_walk<1>(kc, vc, ql, rel_h[b * 3], rel_h[b * 3 + 1], rel_h[b * 3 + 2],
                     wg, dabs, habs, s, a);
    } else {
        const int b = o - 42;
        attn_walk<2>(kc, vc, ql, rel_w[b * 3], rel_w[b * 3 + 1], rel_w[b * 3 + 2],
                     wg, dabs, habs, s, a);
    }

    float4 ov;
    ov.x = a[0] * __builtin_amdgcn_rcpf(s[0]);
    ov.y = a[1] * __builtin_amdgcn_rcpf(s[1]);
    ov.z = a[2] * __builtin_amdgcn_rcpf(s[2]);
    ov.w = a[3] * __builtin_amdgcn_rcpf(s[3]);
    *(float4*)(out + o * SP + (dabs * HH + habs) * WW + wg * 4) = ov;
}

extern "C" void kernel_launch(void* const* d_in, const int* in_sizes, int n_in,
                              void* d_out, int out_size, void* d_ws, size_t ws_size,
                              hipStream_t stream) {
    const float* x     = (const float*)d_in[0];
    const float* w_q   = (const float*)d_in[1];
    const float* w_k   = (const float*)d_in[2];
    const float* w_v   = (const float*)d_in[3];
    const float* rel_d = (const float*)d_in[4];
    const float* rel_h = (const float*)d_in[5];
    const float* rel_w = (const float*)d_in[6];
    float* out = (float*)d_out;

    float* ws = (float*)d_ws;
    float* q  = ws;
    float* k  = ws + (size_t)COUT * SP;
    float* v  = ws + 2 * (size_t)COUT * SP;

    proj<<<dim3(SP / 64, 3), 256, 0, stream>>>(x, w_q, w_k, w_v, q, k, v);
    attn<<<dim3(4, 16, 64), 256, 0, stream>>>(k, v, q, rel_d, rel_h, rel_w, out);
}